// Round 15
// baseline (98.432 us; speedup 1.0000x reference)
//
#include <hip/hip_runtime.h>

#define T_Q 4096
#define S_TOT 8194
#define S_ALLOC 8256
#define SELF_CAP 128
#define NSEG 23
#define NSLOT 24
#define NCH64 129
#define SCALE 0.08838834764831843f   // 1/sqrt(128)
#define NEG_BIG -1.0e30f
#define TS_INF 3.0e38f

typedef __attribute__((ext_vector_type(8))) short short8;
typedef __attribute__((ext_vector_type(4))) float f32x4;
typedef __attribute__((ext_vector_type(4))) unsigned short ush4;
typedef unsigned short ush;
typedef unsigned int uint32;
typedef unsigned long long u64;

static __device__ __forceinline__ ush f2bf(float f) {
    unsigned int u = __float_as_uint(f);
    u += 0x7FFFu + ((u >> 16) & 1u);
    return (ush)(u >> 16);
}
static __device__ __forceinline__ float bf2f(ush u) {
    return __uint_as_float(((unsigned int)u) << 16);
}

// ============ merged prep: self-scan+maskbits | wvo | weights->bf16 (385 blocks) ============
__global__ __launch_bounds__(256) void prep_kernel(
    const float* __restrict__ ets,
    const int* __restrict__ exps, const int* __restrict__ tgtp,
    const float* __restrict__ Wo_s, const float* __restrict__ Wv_s, const float* __restrict__ bv_s,
    const float* __restrict__ Wo_n, const float* __restrict__ Wv_n, const float* __restrict__ bv_n,
    const float* __restrict__ Wq_s, const float* __restrict__ Wq_n,
    const float* __restrict__ Wk_s, const float* __restrict__ Wk_n,
    float* __restrict__ ts_pad, float* __restrict__ ts1, int* __restrict__ perm1,
    u64* __restrict__ maskbits, ush* __restrict__ Wb, float* __restrict__ bvo)
{
    __shared__ __align__(16) ush es[8192];   // scan: staged exps (u16); wvo: aliased as red
    __shared__ int swcnt[4];
    __shared__ int stot;
    float* red = (float*)es;
    int bid = blockIdx.x, tid = threadIdx.x;

    if (bid == 0) {                         // ---- ts_pad + maskbits + self compaction ----
        int tgt = tgtp[0];
        for (int i = tid * 4; i < S_TOT - 2; i += 1024) {
            int4 v = *(const int4*)(exps + i);
            es[i] = (ush)v.x; es[i + 1] = (ush)v.y; es[i + 2] = (ush)v.z; es[i + 3] = (ush)v.w;
        }
        for (int i = tid; i < S_ALLOC; i += 256)
            ts_pad[i] = (i < 2) ? 0.f : ((i < S_TOT) ? ets[i - 2] : TS_INF);
        __syncthreads();
        ush tgt16 = (ush)tgt;
        int w4 = tid >> 6, lane = tid & 63;
        int cbeg = w4 * 33, cend = (w4 == 3) ? NCH64 : (cbeg + 33);
        u64 ltm = ((u64)1 << lane) - 1ull;
        int cnt = 0;
        for (int ch = cbeg; ch < cend; ++ch) {
            int s = ch * 64 + lane;
            bool m = (s < S_TOT) && ((s == 1) || (s >= 2 && es[s - 2] == tgt16));
            u64 b = __ballot(m);
            if (lane == 0) maskbits[ch] = b;
            cnt += __popcll(b);
        }
        if (lane == 0) swcnt[w4] = cnt;
        __syncthreads();
        if (tid == 0) {
            int a = 0;
            #pragma unroll
            for (int i = 0; i < 4; ++i) { int tc = swcnt[i]; swcnt[i] = a; a += tc; }
            stot = a;
        }
        __syncthreads();
        int off2 = swcnt[w4];
        for (int ch = cbeg; ch < cend; ++ch) {
            int s = ch * 64 + lane;
            bool m = (s < S_TOT) && ((s == 1) || (s >= 2 && es[s - 2] == tgt16));
            u64 b = __ballot(m);
            if (m) {
                int p = off2 + __popcll(b & ltm);
                if (p < SELF_CAP) { perm1[p] = s; ts1[p] = (s >= 2) ? ets[s - 2] : 0.f; }
            }
            off2 += __popcll(b);
        }
        __syncthreads();
        int st = stot > SELF_CAP ? SELF_CAP : stot;
        for (int i = st + tid; i < SELF_CAP; i += 256) { perm1[i] = 0; ts1[i] = TS_INF; }
    } else if (bid < 129) {                 // ---- Wvo = Wo@Wv (bf16 slots 4/5), bvo ----
        int row = bid - 1;
        int h = tid >> 7, col = tid & 127;
        const float* Wo = h ? Wo_n : Wo_s;
        const float* Wv = h ? Wv_n : Wv_s;
        const float* bv = h ? bv_n : bv_s;
        float acc = 0.f;
        #pragma unroll 8
        for (int jj = 0; jj < 128; ++jj) acc += Wo[row * 128 + jj] * Wv[jj * 128 + col];
        Wb[(size_t)(4 + h) * 16384 + row * 128 + col] = f2bf(acc);
        red[tid] = Wo[row * 128 + col] * bv[col];
        __syncthreads();
        for (int off = 64; off > 0; off >>= 1) {
            if ((tid & 127) < off) red[tid] += red[tid + off];
            __syncthreads();
        }
        if ((tid & 127) == 0) bvo[h * 128 + row] = red[tid];
    } else {                                // ---- Wq/Wk -> bf16 (slots 0..3) ----
        int idx = (bid - 129) * 256 + tid;
        int which = idx >> 14, e = idx & 16383;
        const float* src;
        switch (which) {
            case 0: src = Wq_s; break; case 1: src = Wq_n; break;
            case 2: src = Wk_s; break; default: src = Wk_n; break;
        }
        Wb[idx] = f2bf(src[e]);
    }
}

// -------- projections, fused encode (fast trig).  y<4: swapped MFMA -> coalesced ush4 stores
__global__ __launch_bounds__(256) void proj_kernel(
    const float* __restrict__ t, const float* __restrict__ ets, const float* __restrict__ bf,
    const ush* __restrict__ Wb,
    const float* __restrict__ bq_s, const float* __restrict__ bq_n,
    const float* __restrict__ bk_s, const float* __restrict__ bk_n,
    const float* __restrict__ bvo, const int* __restrict__ perm1,
    ush* __restrict__ qp, ush* __restrict__ kpc, ush* __restrict__ vpoT)
{
    __shared__ float bfs[64];
    int tid = threadIdx.x;
    if (tid < 64) bfs[tid] = bf[tid];
    __syncthreads();

    int y = blockIdx.y;
    const float* b; int M; const int* perm = nullptr; int ldv = 0;
    ush* out = nullptr; ush* outT = nullptr;
    switch (y) {
        case 0: b = bq_s;      M = T_Q; out = qp; break;
        case 1: b = bq_n;      M = T_Q; out = qp + (size_t)T_Q * 128; break;
        case 2: b = bk_s;      M = SELF_CAP; perm = perm1; out = kpc; break;
        case 3: b = bk_n;      M = S_ALLOC;  out = kpc + (size_t)SELF_CAP * 128; break;
        case 4: b = bvo;       M = SELF_CAP; perm = perm1; outT = vpoT; ldv = SELF_CAP; break;
        default:b = bvo + 128; M = S_ALLOC;  outT = vpoT + (size_t)SELF_CAP * 128; ldv = S_ALLOC; break;
    }
    int mbase = blockIdx.x * 64 + (tid >> 6) * 16;
    if (mbase >= M) return;
    int lane = tid & 63, u = lane >> 4, c = lane & 15;

    // --- fused encode: x for this lane's source row ---
    float x;
    if (y < 2) {
        x = t[mbase + c];
    } else if (perm) {
        int s = perm[mbase + c];                 // pads -> 0 (masked via ts1=TS_INF)
        x = (s >= 2) ? ets[s - 2] : 0.f;
    } else {
        int s = mbase + c;                       // pads 8194.. -> 0 (masked via ts_pad=TS_INF)
        x = (s >= 2 && s < S_TOT) ? ets[s - 2] : 0.f;
    }
    short8 af[4];
    #pragma unroll
    for (int ks = 0; ks < 4; ++ks) {
        #pragma unroll
        for (int i = 0; i < 8; ++i) {
            float m = x * bfs[(ks & 1) * 32 + u * 8 + i];
            float v = (ks < 2) ? __cosf(m) : __sinf(m);   // fast HW trig: |m| < 0.2 rad
            af[ks][i] = (short)f2bf(v * SCALE);
        }
    }

    const ush* W = Wb + (size_t)y * 16384;
    if (!outT) {
        // swapped operands: D[ncol][phi_row]; lane holds phi row (mbase+c), ncols u*4+r
        #pragma unroll
        for (int nt = 0; nt < 8; ++nt) {
            f32x4 acc = *(const f32x4*)(b + nt * 16 + u * 4);
            #pragma unroll
            for (int ks = 0; ks < 4; ++ks) {
                short8 wf = *(const short8*)(W + (nt * 16 + c) * 128 + ks * 32 + u * 8);
                acc = __builtin_amdgcn_mfma_f32_16x16x32_bf16(wf, af[ks], acc, 0, 0, 0);
            }
            ush4 pk;
            #pragma unroll
            for (int r = 0; r < 4; ++r) pk[r] = f2bf(acc[r]);
            *(ush4*)(out + (size_t)(mbase + c) * 128 + nt * 16 + u * 4) = pk;
        }
    } else {
        // original order: D[phi_row][ncol]; lane holds ncol (nt*16+c), rows mbase+u*4+r
        #pragma unroll
        for (int nt = 0; nt < 8; ++nt) {
            int ncol = nt * 16 + c;
            float bval = b[ncol];
            f32x4 acc = {bval, bval, bval, bval};
            #pragma unroll
            for (int ks = 0; ks < 4; ++ks) {
                short8 wf = *(const short8*)(W + ncol * 128 + ks * 32 + u * 8);
                acc = __builtin_amdgcn_mfma_f32_16x16x32_bf16(af[ks], wf, acc, 0, 0, 0);
            }
            ush4 pk;
            #pragma unroll
            for (int r = 0; r < 4; ++r) pk[r] = f2bf(acc[r]);
            *(ush4*)(outT + (size_t)ncol * ldv + mbase + u * 4) = pk;
        }
    }
}

// ----- flash attention: K AND V double-buffered, ONE barrier per tile, NSEG=23 ------------
__global__ __launch_bounds__(256, 2) void attn_kernel(
    const ush* __restrict__ qp, const ush* __restrict__ kpc, const ush* __restrict__ vpoT,
    const float* __restrict__ ts_pad, const float* __restrict__ ts1,
    const u64* __restrict__ maskbits, const float* __restrict__ tq,
    ush* __restrict__ Opart, float* __restrict__ mpart, float* __restrict__ lpart)
{
    // XCD-chunked bijective swizzle: 768 = 8 XCDs x 96 blocks
    int bid = ((int)blockIdx.x & 7) * 96 + ((int)blockIdx.x >> 3);
    int head, qb, slot, t0, t1;
    if (bid < 32 * NSEG) {
        head = 1; int seg = bid >> 5; qb = bid & 31; slot = seg;
        t0 = seg * NCH64 / NSEG; t1 = (seg + 1) * NCH64 / NSEG;
    } else {
        head = 0; qb = bid - 32 * NSEG; slot = NSEG; t0 = 0; t1 = SELF_CAP / 64;
    }
    const ush* kph = kpc  + (head ? (size_t)SELF_CAP * 128 : 0);
    const ush* vph = vpoT + (head ? (size_t)SELF_CAP * 128 : 0);
    const int ld = head ? S_ALLOC : SELF_CAP;
    const float* tsh = head ? ts_pad : ts1;
    const ush* qph = qp + (head ? (size_t)T_Q * 128 : 0);

    __shared__ __align__(16) ush K2[2][64 * 128];   // [key][d], XOR-swizzled, dbuf
    __shared__ __align__(16) ush V2[2][128 * 64];   // [d][key], XOR-swizzled, dbuf
    __shared__ float tsb[2][64];

    int tid = threadIdx.x, w = tid >> 6, lane = tid & 63;
    int u = lane >> 4, c = lane & 15;
    int qrow0 = qb * 128 + w * 32;
    int sbase = (lane & 48) + ((lane & 48) >> 2);

    short8 qf[2][4];
    #pragma unroll
    for (int qg = 0; qg < 2; ++qg) {
        const ush* qr = qph + (size_t)(qrow0 + qg * 16 + c) * 128;
        #pragma unroll
        for (int ks = 0; ks < 4; ++ks) qf[qg][ks] = *(const short8*)(qr + ks * 32 + u * 8);
    }
    float t_c[2] = { tq[qrow0 + c], tq[qrow0 + 16 + c] };

    f32x4 Ov[2][8];
    #pragma unroll
    for (int qg = 0; qg < 2; ++qg)
        #pragma unroll
        for (int dt = 0; dt < 8; ++dt) Ov[qg][dt] = (f32x4){0.f, 0.f, 0.f, 0.f};
    float mrow[2] = {NEG_BIG, NEG_BIG}, lrow[2] = {0.f, 0.f};

    short8 kreg[4], vreg[4]; float tsreg = 0.f;
    int kr = tid >> 2, kq = tid & 3;      // K staging: row 0..63, chunk-quad
    int vd = tid >> 1, vh = tid & 1;      // V staging: d-row 0..127, half

    auto LOADT = [&](int t) {
        int kb = t * 64;
        const ush* src = kph + (size_t)(kb + kr) * 128 + kq * 32;
        #pragma unroll
        for (int i = 0; i < 4; ++i) kreg[i] = *(const short8*)(src + i * 8);
        const ush* vsrc = vph + (size_t)vd * ld + kb + vh * 32;
        #pragma unroll
        for (int i = 0; i < 4; ++i) vreg[i] = *(const short8*)(vsrc + i * 8);
        if (tid < 64) tsreg = tsh[kb + tid];
    };
    auto WRITE_KV = [&](int b) {
        #pragma unroll
        for (int i = 0; i < 4; ++i)
            *(short8*)&K2[b][kr * 128 + (((kq * 4 + i) ^ (kr & 7)) << 3)] = kreg[i];
        #pragma unroll
        for (int i = 0; i < 4; ++i)
            *(short8*)&V2[b][vd * 64 + (((vh * 4 + i) ^ (vd & 7)) << 3)] = vreg[i];
        if (tid < 64) tsb[b][tid] = tsreg;
    };

    LOADT(t0); WRITE_KV(0);
    __syncthreads();

    for (int t = t0; t < t1; ++t) {
        int cur = (t - t0) & 1;
        bool pre = (t + 1 < t1);
        u64 mk = head ? maskbits[t] : 0ull;
        if (pre) LOADT(t + 1);

        // --- QK^T swapped: lane owns queries qg*16+c, keys ct*16+u*4+r ---
        float sc[2][4][4];
        #pragma unroll
        for (int ct = 0; ct < 4; ++ct) {
            short8 kf[4];
            int row = ct * 16 + c;
            #pragma unroll
            for (int ks = 0; ks < 4; ++ks)
                kf[ks] = *(const short8*)&K2[cur][row * 128 + (((ks * 4 + u) ^ (row & 7)) << 3)];
            f32x4 acc0 = {0.f, 0.f, 0.f, 0.f}, acc1 = {0.f, 0.f, 0.f, 0.f};
            #pragma unroll
            for (int ks = 0; ks < 4; ++ks) {
                acc0 = __builtin_amdgcn_mfma_f32_16x16x32_bf16(kf[ks], qf[0][ks], acc0, 0, 0, 0);
                acc1 = __builtin_amdgcn_mfma_f32_16x16x32_bf16(kf[ks], qf[1][ks], acc1, 0, 0, 0);
            }
            f32x4 ts4 = *(const f32x4*)&tsb[cur][ct * 16 + u * 4];
            uint32 mh = (uint32)(mk >> (ct * 16 + u * 4));
            #pragma unroll
            for (int r = 0; r < 4; ++r) {
                bool em = (mh >> r) & 1u;
                sc[0][ct][r] = (em || ts4[r] > t_c[0]) ? NEG_BIG : acc0[r] * SCALE;
                sc[1][ct][r] = (em || ts4[r] > t_c[1]) ? NEG_BIG : acc1[r] * SCALE;
            }
        }
        if (pre) WRITE_KV(cur ^ 1);   // writes go to the buffer no wave reads this tile

        // --- in-register online softmax (exact trigger) + pack ---
        short8 pfq[2][2];
        #pragma unroll
        for (int qg = 0; qg < 2; ++qg) {
            float m0 = fmaxf(fmaxf(sc[qg][0][0], sc[qg][0][1]), fmaxf(sc[qg][0][2], sc[qg][0][3]));
            float m1 = fmaxf(fmaxf(sc[qg][1][0], sc[qg][1][1]), fmaxf(sc[qg][1][2], sc[qg][1][3]));
            float m2 = fmaxf(fmaxf(sc[qg][2][0], sc[qg][2][1]), fmaxf(sc[qg][2][2], sc[qg][2][3]));
            float m3 = fmaxf(fmaxf(sc[qg][3][0], sc[qg][3][1]), fmaxf(sc[qg][3][2], sc[qg][3][3]));
            float mt = fmaxf(fmaxf(m0, m1), fmaxf(m2, m3));
            mt = fmaxf(mt, __shfl_xor(mt, 16));
            mt = fmaxf(mt, __shfl_xor(mt, 32));
            if (__any(mt > mrow[qg])) {
                float mnew = fmaxf(mrow[qg], mt);
                float sf = __expf(mrow[qg] - mnew);
                mrow[qg] = mnew;
                lrow[qg] *= sf;
                float sfr[4];
                #pragma unroll
                for (int r = 0; r < 4; ++r) sfr[r] = __shfl(sf, sbase + r);
                #pragma unroll
                for (int dt = 0; dt < 8; ++dt) {
                    Ov[qg][dt][0] *= sfr[0]; Ov[qg][dt][1] *= sfr[1];
                    Ov[qg][dt][2] *= sfr[2]; Ov[qg][dt][3] *= sfr[3];
                }
            }
            float p[4][4];
            #pragma unroll
            for (int ct = 0; ct < 4; ++ct)
                #pragma unroll
                for (int r = 0; r < 4; ++r) p[ct][r] = __expf(sc[qg][ct][r] - mrow[qg]);
            float s0 = (p[0][0] + p[0][1]) + (p[0][2] + p[0][3]);
            float s1 = (p[1][0] + p[1][1]) + (p[1][2] + p[1][3]);
            float s2 = (p[2][0] + p[2][1]) + (p[2][2] + p[2][3]);
            float s3 = (p[3][0] + p[3][1]) + (p[3][2] + p[3][3]);
            float s16 = (s0 + s1) + (s2 + s3);
            s16 += __shfl_xor(s16, 16);
            s16 += __shfl_xor(s16, 32);
            lrow[qg] += s16;

            uint32 q0[4], q1[4];
            #pragma unroll
            for (int ct = 0; ct < 4; ++ct) {
                asm("v_cvt_pk_bf16_f32 %0, %1, %2" : "=v"(q0[ct]) : "v"(p[ct][0]), "v"(p[ct][1]));
                asm("v_cvt_pk_bf16_f32 %0, %1, %2" : "=v"(q1[ct]) : "v"(p[ct][2]), "v"(p[ct][3]));
            }
            #pragma unroll
            for (int ksl = 0; ksl < 2; ++ksl) {
                uint32 a0 = q0[2 * ksl], b0 = q0[2 * ksl + 1];
                uint32 a1 = q1[2 * ksl], b1 = q1[2 * ksl + 1];
                asm("v_permlane32_swap_b32 %0, %1" : "+v"(a0), "+v"(b0));
                asm("v_permlane16_swap_b32 %0, %1" : "+v"(a0), "+v"(b0));
                asm("v_permlane32_swap_b32 %0, %1" : "+v"(a1), "+v"(b1));
                asm("v_permlane16_swap_b32 %0, %1" : "+v"(a1), "+v"(b1));
                union { uint32 w4[4]; short8 s8; } pk_;
                pk_.w4[0] = a0; pk_.w4[1] = a1; pk_.w4[2] = b0; pk_.w4[3] = b1;
                pfq[qg][ksl] = pk_.s8;
            }
        }

        // --- PV: V read once per fragment, used by both query groups ---
        #pragma unroll
        for (int ksl = 0; ksl < 2; ++ksl)
            #pragma unroll
            for (int dt = 0; dt < 8; ++dt) {
                int d = dt * 16 + c;
                short8 vf = *(const short8*)&V2[cur][d * 64 + (((ksl * 4 + u) ^ (d & 7)) << 3)];
                Ov[0][dt] = __builtin_amdgcn_mfma_f32_16x16x32_bf16(pfq[0][ksl], vf, Ov[0][dt], 0, 0, 0);
                Ov[1][dt] = __builtin_amdgcn_mfma_f32_16x16x32_bf16(pfq[1][ksl], vf, Ov[1][dt], 0, 0, 0);
            }

        __syncthreads();   // single barrier: all waves done reading buf[cur] before next
                           // iteration overwrites it (next iter writes buf[cur])
    }

    // --- bf16 O partials + fp32 m/l ---
    size_t rbase = (size_t)slot * T_Q + qrow0;
    #pragma unroll
    for (int qg = 0; qg < 2; ++qg)
        #pragma unroll
        for (int dt = 0; dt < 8; ++dt)
            #pragma unroll
            for (int r = 0; r < 4; ++r)
                Opart[(rbase + qg * 16 + u * 4 + r) * 128 + dt * 16 + c] = f2bf(Ov[qg][dt][r]);
    if (u == 0) {
        mpart[rbase + c] = mrow[0];      lpart[rbase + c] = lrow[0];
        mpart[rbase + 16 + c] = mrow[1]; lpart[rbase + 16 + c] = lrow[1];
    }
}

// ---------------- combine partials + output bias + lambda head ----------------
__global__ __launch_bounds__(256) void combine_kernel(
    const ush* __restrict__ Opart, const float* __restrict__ mpart, const float* __restrict__ lpart,
    const float* __restrict__ bo_s, const float* __restrict__ bo_n,
    const float* __restrict__ Wl, const float* __restrict__ bl,
    const float* __restrict__ phi, float* __restrict__ outp)
{
    int row = blockIdx.x, tid = threadIdx.x;
    float outv;
    if (tid < 128) {               // self head: single partial (slot NSEG)
        size_t rb = (size_t)NSEG * T_Q + row;
        outv = bf2f(Opart[rb * 128 + tid]) / lpart[rb] + bo_s[tid];
    } else {                       // neighbor head: merge NSEG partials
        int d = tid - 128;
        float M = NEG_BIG;
        #pragma unroll
        for (int z = 0; z < NSEG; ++z) M = fmaxf(M, mpart[(size_t)z * T_Q + row]);
        float L = 0.f, O = 0.f;
        #pragma unroll
        for (int z = 0; z < NSEG; ++z) {
            size_t rb = (size_t)z * T_Q + row;
            float wz = __expf(mpart[rb] - M);
            L += wz * lpart[rb];
            O += wz * bf2f(Opart[rb * 128 + d]);
        }
        outv = O / L + bo_n[d];
    }
    outp[T_Q + (size_t)row * 256 + tid] = outv;

    float dot = outv * Wl[tid];
    #pragma unroll
    for (int off = 1; off < 64; off <<= 1) dot += __shfl_xor(dot, off);
    __shared__ float wsum[4];
    if ((tid & 63) == 0) wsum[tid >> 6] = dot;
    __syncthreads();
    if (tid == 0) {
        float s = wsum[0] + wsum[1] + wsum[2] + wsum[3];
        float ph = phi[0];
        float x = (s + bl[0]) * ph;
        x = fminf(x, 20.0f);
        outp[row] = log1pf(__expf(x)) / ph;
    }
}

extern "C" void kernel_launch(void* const* d_in, const int* in_sizes, int n_in,
                              void* d_out, int out_size, void* d_ws, size_t ws_size,
                              hipStream_t stream) {
    (void)in_sizes; (void)n_in; (void)out_size; (void)ws_size;
    const float* t    = (const float*)d_in[0];
    const float* ets  = (const float*)d_in[1];
    const int*   exps = (const int*)d_in[2];
    const int*   tgt  = (const int*)d_in[3];
    const float* bfq  = (const float*)d_in[4];
    const float* phi  = (const float*)d_in[5];
    const float* Wlin = (const float*)d_in[6];
    const float* blin = (const float*)d_in[7];
    const float* Wq_s = (const float*)d_in[8];
    const float* Wk_s = (const float*)d_in[9];
    const float* Wv_s = (const float*)d_in[10];
    const float* Wo_s = (const float*)d_in[11];
    const float* bq_s = (const float*)d_in[12];
    const float* bk_s = (const float*)d_in[13];
    const float* bv_s = (const float*)d_in[14];
    const float* bo_s = (const float*)d_in[15];
    const float* Wq_n = (const float*)d_in[16];
    const float* Wk_n = (const float*)d_in[17];
    const float* Wv_n = (const float*)d_in[18];
    const float* Wo_n = (const float*)d_in[19];
    const float* bq_n = (const float*)d_in[20];
    const float* bk_n = (const float*)d_in[21];
    const float* bv_n = (const float*)d_in[22];
    const float* bo_n = (const float*)d_in[23];

    char* ws = (char*)d_ws;
    size_t off = 0;
    auto alloc = [&](size_t bytes) { void* p = ws + off; off += (bytes + 255) & ~(size_t)255; return p; };
    ush* qpb    = (ush*)alloc((size_t)2 * T_Q * 128 * 2);
    ush* kpc    = (ush*)alloc((size_t)(SELF_CAP + S_ALLOC) * 128 * 2);
    ush* vpoT   = (ush*)alloc((size_t)128 * (SELF_CAP + S_ALLOC) * 2);
    int*    perm1 = (int*)   alloc((size_t)SELF_CAP * 4);
    float*  ts1   = (float*) alloc((size_t)SELF_CAP * 4);
    float*  ts_pad= (float*) alloc((size_t)S_ALLOC * 4);
    u64*    maskb = (u64*)   alloc((size_t)NCH64 * 8);
    float*  bvo   = (float*) alloc((size_t)2 * 128 * 4);
    ush*    Wb    = (ush*)   alloc((size_t)6 * 16384 * 2);
    ush*    Opart = (ush*)   alloc((size_t)NSLOT * T_Q * 128 * 2);
    float*  mpart = (float*) alloc((size_t)NSLOT * T_Q * 4);
    float*  lpart = (float*) alloc((size_t)NSLOT * T_Q * 4);

    float* outp = (float*)d_out;

    prep_kernel<<<dim3(385), dim3(256), 0, stream>>>(
        ets, exps, tgt, Wo_s, Wv_s, bv_s, Wo_n, Wv_n, bv_n,
        Wq_s, Wq_n, Wk_s, Wk_n, ts_pad, ts1, perm1, maskb, Wb, bvo);
    proj_kernel<<<dim3(129, 6), dim3(256), 0, stream>>>(
        t, ets, bfq, Wb, bq_s, bq_n, bk_s, bk_n, bvo, perm1, qpb, kpc, vpoT);
    attn_kernel<<<dim3(32 * NSEG + 32), dim3(256), 0, stream>>>(
        qpb, kpc, vpoT, ts_pad, ts1, maskb, t, Opart, mpart, lpart);
    combine_kernel<<<dim3(T_Q), dim3(256), 0, stream>>>(
        Opart, mpart, lpart, bo_s, bo_n, Wlin, blin, phi, outp);
}

// Round 16
// 95.488 us; speedup vs baseline: 1.0308x; 1.0308x over previous
//
#include <hip/hip_runtime.h>

#define T_Q 4096
#define S_TOT 8194
#define S_ALLOC 8256
#define SELF_CAP 128
#define NSEG 23
#define NSLOT 24
#define NCH64 129
#define SCALE 0.08838834764831843f   // 1/sqrt(128)
#define NEG_BIG -1.0e30f
#define TS_INF 3.0e38f

typedef __attribute__((ext_vector_type(8))) short short8;
typedef __attribute__((ext_vector_type(4))) float f32x4;
typedef __attribute__((ext_vector_type(4))) unsigned short ush4;
typedef unsigned short ush;
typedef unsigned int uint32;
typedef unsigned long long u64;

static __device__ __forceinline__ ush f2bf(float f) {
    unsigned int u = __float_as_uint(f);
    u += 0x7FFFu + ((u >> 16) & 1u);
    return (ush)(u >> 16);
}
static __device__ __forceinline__ float bf2f(ush u) {
    return __uint_as_float(((unsigned int)u) << 16);
}

// ============ merged prep: encode | self-scan+maskbits | wvo | weights->bf16 ============
__global__ __launch_bounds__(256) void prep_kernel(
    const float* __restrict__ t, const float* __restrict__ ets,
    const int* __restrict__ exps, const int* __restrict__ tgtp,
    const float* __restrict__ bf,
    const float* __restrict__ Wo_s, const float* __restrict__ Wv_s, const float* __restrict__ bv_s,
    const float* __restrict__ Wo_n, const float* __restrict__ Wv_n, const float* __restrict__ bv_n,
    const float* __restrict__ Wq_s, const float* __restrict__ Wq_n,
    const float* __restrict__ Wk_s, const float* __restrict__ Wk_n,
    ush* __restrict__ phi_t, ush* __restrict__ phi_ts,
    float* __restrict__ ts_pad, float* __restrict__ ts1, int* __restrict__ perm1,
    u64* __restrict__ maskbits, ush* __restrict__ Wb, float* __restrict__ bvo)
{
    __shared__ __align__(16) ush es[8192];   // scan: staged exps (u16); wvo: aliased as red
    __shared__ int swcnt[4];
    __shared__ int stot;
    float* red = (float*)es;
    int bid = blockIdx.x, tid = threadIdx.x;

    if (bid < 3088) {                       // ---- harmonic encode (fast trig: |arg| < 0.2 rad) ----
        int R = bid * 4 + (tid >> 6);
        int j = tid & 63;
        float x; ush* dst;
        if (R < T_Q) { x = t[R]; dst = phi_t + (size_t)R * 128; }
        else {
            int s = R - T_Q;
            x = (s < 2) ? 0.0f : ((s < S_TOT) ? ets[s - 2] : 0.0f);
            dst = phi_ts + (size_t)s * 128;
        }
        float m = x * bf[j];
        dst[j]      = f2bf(__cosf(m) * SCALE);
        dst[64 + j] = f2bf(__sinf(m) * SCALE);
    } else if (bid == 3088) {               // ---- ts_pad + maskbits + self compaction ----
        int tgt = tgtp[0];
        for (int i = tid * 4; i < S_TOT - 2; i += 1024) {
            int4 v = *(const int4*)(exps + i);
            es[i] = (ush)v.x; es[i + 1] = (ush)v.y; es[i + 2] = (ush)v.z; es[i + 3] = (ush)v.w;
        }
        for (int i = tid; i < S_ALLOC; i += 256)
            ts_pad[i] = (i < 2) ? 0.f : ((i < S_TOT) ? ets[i - 2] : TS_INF);
        __syncthreads();
        ush tgt16 = (ush)tgt;
        int w4 = tid >> 6, lane = tid & 63;
        int cbeg = w4 * 33, cend = (w4 == 3) ? NCH64 : (cbeg + 33);
        u64 ltm = ((u64)1 << lane) - 1ull;
        int cnt = 0;
        for (int ch = cbeg; ch < cend; ++ch) {
            int s = ch * 64 + lane;
            bool m = (s < S_TOT) && ((s == 1) || (s >= 2 && es[s - 2] == tgt16));
            u64 b = __ballot(m);
            if (lane == 0) maskbits[ch] = b;
            cnt += __popcll(b);
        }
        if (lane == 0) swcnt[w4] = cnt;
        __syncthreads();
        if (tid == 0) {
            int a = 0;
            #pragma unroll
            for (int i = 0; i < 4; ++i) { int tc = swcnt[i]; swcnt[i] = a; a += tc; }
            stot = a;
        }
        __syncthreads();
        int off2 = swcnt[w4];
        for (int ch = cbeg; ch < cend; ++ch) {
            int s = ch * 64 + lane;
            bool m = (s < S_TOT) && ((s == 1) || (s >= 2 && es[s - 2] == tgt16));
            u64 b = __ballot(m);
            if (m) {
                int p = off2 + __popcll(b & ltm);
                if (p < SELF_CAP) { perm1[p] = s; ts1[p] = (s >= 2) ? ets[s - 2] : 0.f; }
            }
            off2 += __popcll(b);
        }
        __syncthreads();
        int st = stot > SELF_CAP ? SELF_CAP : stot;
        for (int i = st + tid; i < SELF_CAP; i += 256) { perm1[i] = 0; ts1[i] = TS_INF; }
    } else if (bid < 3217) {                // ---- Wvo = Wo@Wv (bf16 slots 4/5), bvo ----
        int row = bid - 3089;
        int h = tid >> 7, col = tid & 127;
        const float* Wo = h ? Wo_n : Wo_s;
        const float* Wv = h ? Wv_n : Wv_s;
        const float* bv = h ? bv_n : bv_s;
        float acc = 0.f;
        #pragma unroll 8
        for (int jj = 0; jj < 128; ++jj) acc += Wo[row * 128 + jj] * Wv[jj * 128 + col];
        Wb[(size_t)(4 + h) * 16384 + row * 128 + col] = f2bf(acc);
        red[tid] = Wo[row * 128 + col] * bv[col];
        __syncthreads();
        for (int off = 64; off > 0; off >>= 1) {
            if ((tid & 127) < off) red[tid] += red[tid + off];
            __syncthreads();
        }
        if ((tid & 127) == 0) bvo[h * 128 + row] = red[tid];
    } else {                                // ---- Wq/Wk -> bf16 (slots 0..3) ----
        int idx = (bid - 3217) * 256 + tid;
        int which = idx >> 14, e = idx & 16383;
        const float* src;
        switch (which) {
            case 0: src = Wq_s; break; case 1: src = Wq_n; break;
            case 2: src = Wk_s; break; default: src = Wk_n; break;
        }
        Wb[idx] = f2bf(src[e]);
    }
}

// ---------------- projections: 0=q_s 1=q_n 2=k_s 3=k_n 4=v_s^T 5=v_n^T ----------------
__global__ __launch_bounds__(256) void proj_kernel(
    const ush* __restrict__ phi_t, const ush* __restrict__ phi_ts, const ush* __restrict__ Wb,
    const float* __restrict__ bq_s, const float* __restrict__ bq_n,
    const float* __restrict__ bk_s, const float* __restrict__ bk_n,
    const float* __restrict__ bvo, const int* __restrict__ perm1,
    ush* __restrict__ qp, ush* __restrict__ kpc, ush* __restrict__ vpoT)
{
    int y = blockIdx.y;
    const float* b; int M; const int* perm = nullptr; int ldv = 0;
    const ush* in = phi_ts;
    ush* out = nullptr; ush* outT = nullptr;
    switch (y) {
        case 0: b = bq_s;      M = T_Q; in = phi_t; out = qp; break;
        case 1: b = bq_n;      M = T_Q; in = phi_t; out = qp + (size_t)T_Q * 128; break;
        case 2: b = bk_s;      M = SELF_CAP; perm = perm1; out = kpc; break;
        case 3: b = bk_n;      M = S_ALLOC;  out = kpc + (size_t)SELF_CAP * 128; break;
        case 4: b = bvo;       M = SELF_CAP; perm = perm1; outT = vpoT; ldv = SELF_CAP; break;
        default:b = bvo + 128; M = S_ALLOC;  outT = vpoT + (size_t)SELF_CAP * 128; ldv = S_ALLOC; break;
    }
    int mbase = blockIdx.x * 64 + (int)(threadIdx.x >> 6) * 16;
    if (mbase >= M) return;
    int lane = threadIdx.x & 63, u = lane >> 4, c = lane & 15;
    const ush* arow = perm ? (in + (size_t)perm[mbase + c] * 128)
                           : (in + (size_t)(mbase + c) * 128);
    short8 af[4];
    #pragma unroll
    for (int ks = 0; ks < 4; ++ks) af[ks] = *(const short8*)(arow + ks * 32 + u * 8);
    const ush* W = Wb + (size_t)y * 16384;
    #pragma unroll
    for (int nt = 0; nt < 8; ++nt) {
        int ncol = nt * 16 + c;
        float bval = b[ncol];
        f32x4 acc = {bval, bval, bval, bval};
        #pragma unroll
        for (int ks = 0; ks < 4; ++ks) {
            short8 bf8 = *(const short8*)(W + ncol * 128 + ks * 32 + u * 8);
            acc = __builtin_amdgcn_mfma_f32_16x16x32_bf16(af[ks], bf8, acc, 0, 0, 0);
        }
        if (outT) {
            ush4 pk;
            #pragma unroll
            for (int r = 0; r < 4; ++r) pk[r] = f2bf(acc[r]);
            *(ush4*)(outT + (size_t)ncol * ldv + mbase + u * 4) = pk;
        } else {
            #pragma unroll
            for (int r = 0; r < 4; ++r)
                out[(size_t)(mbase + u * 4 + r) * 128 + ncol] = f2bf(acc[r]);
        }
    }
}

// ----- flash attention: round-10 proven structure (K dbuf, V single), NSEG=23, lb(256,2) --
__global__ __launch_bounds__(256, 2) void attn_kernel(
    const ush* __restrict__ qp, const ush* __restrict__ kpc, const ush* __restrict__ vpoT,
    const float* __restrict__ ts_pad, const float* __restrict__ ts1,
    const u64* __restrict__ maskbits, const float* __restrict__ tq,
    ush* __restrict__ Opart, float* __restrict__ mpart, float* __restrict__ lpart)
{
    // XCD-chunked bijective swizzle: 768 = 8 XCDs x 96 blocks
    int bid = ((int)blockIdx.x & 7) * 96 + ((int)blockIdx.x >> 3);
    int head, qb, slot, t0, t1;
    if (bid < 32 * NSEG) {
        head = 1; int seg = bid >> 5; qb = bid & 31; slot = seg;
        t0 = seg * NCH64 / NSEG; t1 = (seg + 1) * NCH64 / NSEG;
    } else {
        head = 0; qb = bid - 32 * NSEG; slot = NSEG; t0 = 0; t1 = SELF_CAP / 64;
    }
    const ush* kph = kpc  + (head ? (size_t)SELF_CAP * 128 : 0);
    const ush* vph = vpoT + (head ? (size_t)SELF_CAP * 128 : 0);
    const int ld = head ? S_ALLOC : SELF_CAP;
    const float* tsh = head ? ts_pad : ts1;
    const ush* qph = qp + (head ? (size_t)T_Q * 128 : 0);

    __shared__ __align__(16) ush K2[2][64 * 128];   // [key][d], XOR-swizzled, dbuf
    __shared__ __align__(16) ush V1[128 * 64];      // [d][key], XOR-swizzled, single
    __shared__ float tsb[2][64];

    int tid = threadIdx.x, w = tid >> 6, lane = tid & 63;
    int u = lane >> 4, c = lane & 15;
    int qrow0 = qb * 128 + w * 32;
    int sbase = (lane & 48) + ((lane & 48) >> 2);

    short8 qf[2][4];
    #pragma unroll
    for (int qg = 0; qg < 2; ++qg) {
        const ush* qr = qph + (size_t)(qrow0 + qg * 16 + c) * 128;
        #pragma unroll
        for (int ks = 0; ks < 4; ++ks) qf[qg][ks] = *(const short8*)(qr + ks * 32 + u * 8);
    }
    float t_c[2] = { tq[qrow0 + c], tq[qrow0 + 16 + c] };

    f32x4 Ov[2][8];
    #pragma unroll
    for (int qg = 0; qg < 2; ++qg)
        #pragma unroll
        for (int dt = 0; dt < 8; ++dt) Ov[qg][dt] = (f32x4){0.f, 0.f, 0.f, 0.f};
    float mrow[2] = {NEG_BIG, NEG_BIG}, lrow[2] = {0.f, 0.f};

    short8 kreg[4], vreg[4]; float tsreg = 0.f;
    int kr = tid >> 2, kq = tid & 3;      // K staging: row 0..63, chunk-quad
    int vd = tid >> 1, vh = tid & 1;      // V staging: d-row 0..127, half

    auto LOADT = [&](int t) {
        int kb = t * 64;
        const ush* src = kph + (size_t)(kb + kr) * 128 + kq * 32;
        #pragma unroll
        for (int i = 0; i < 4; ++i) kreg[i] = *(const short8*)(src + i * 8);
        const ush* vsrc = vph + (size_t)vd * ld + kb + vh * 32;
        #pragma unroll
        for (int i = 0; i < 4; ++i) vreg[i] = *(const short8*)(vsrc + i * 8);
        if (tid < 64) tsreg = tsh[kb + tid];
    };
    auto WRITE_K = [&](int b) {
        #pragma unroll
        for (int i = 0; i < 4; ++i)
            *(short8*)&K2[b][kr * 128 + (((kq * 4 + i) ^ (kr & 7)) << 3)] = kreg[i];
        if (tid < 64) tsb[b][tid] = tsreg;
    };
    auto WRITE_V = [&]() {
        #pragma unroll
        for (int i = 0; i < 4; ++i)
            *(short8*)&V1[vd * 64 + (((vh * 4 + i) ^ (vd & 7)) << 3)] = vreg[i];
    };

    LOADT(t0); WRITE_K(0); WRITE_V();
    __syncthreads();

    for (int t = t0; t < t1; ++t) {
        int cur = (t - t0) & 1;
        bool pre = (t + 1 < t1);
        u64 mk = head ? maskbits[t] : 0ull;
        if (pre) LOADT(t + 1);

        // --- QK^T swapped: lane owns queries qg*16+c, keys ct*16+u*4+r ---
        float sc[2][4][4];
        #pragma unroll
        for (int ct = 0; ct < 4; ++ct) {
            short8 kf[4];
            int row = ct * 16 + c;
            #pragma unroll
            for (int ks = 0; ks < 4; ++ks)
                kf[ks] = *(const short8*)&K2[cur][row * 128 + (((ks * 4 + u) ^ (row & 7)) << 3)];
            f32x4 acc0 = {0.f, 0.f, 0.f, 0.f}, acc1 = {0.f, 0.f, 0.f, 0.f};
            #pragma unroll
            for (int ks = 0; ks < 4; ++ks) {
                acc0 = __builtin_amdgcn_mfma_f32_16x16x32_bf16(kf[ks], qf[0][ks], acc0, 0, 0, 0);
                acc1 = __builtin_amdgcn_mfma_f32_16x16x32_bf16(kf[ks], qf[1][ks], acc1, 0, 0, 0);
            }
            f32x4 ts4 = *(const f32x4*)&tsb[cur][ct * 16 + u * 4];
            uint32 mh = (uint32)(mk >> (ct * 16 + u * 4));
            #pragma unroll
            for (int r = 0; r < 4; ++r) {
                bool em = (mh >> r) & 1u;
                sc[0][ct][r] = (em || ts4[r] > t_c[0]) ? NEG_BIG : acc0[r] * SCALE;
                sc[1][ct][r] = (em || ts4[r] > t_c[1]) ? NEG_BIG : acc1[r] * SCALE;
            }
        }
        if (pre) WRITE_K(cur ^ 1);

        // --- in-register online softmax (exact trigger) + pack ---
        short8 pfq[2][2];
        #pragma unroll
        for (int qg = 0; qg < 2; ++qg) {
            float mt = sc[qg][0][0];
            #pragma unroll
            for (int ct = 0; ct < 4; ++ct)
                #pragma unroll
                for (int r = 0; r < 4; ++r) mt = fmaxf(mt, sc[qg][ct][r]);
            mt = fmaxf(mt, __shfl_xor(mt, 16));
            mt = fmaxf(mt, __shfl_xor(mt, 32));
            if (__any(mt > mrow[qg])) {
                float mnew = fmaxf(mrow[qg], mt);
                float sf = __expf(mrow[qg] - mnew);
                mrow[qg] = mnew;
                lrow[qg] *= sf;
                float sfr[4];
                #pragma unroll
                for (int r = 0; r < 4; ++r) sfr[r] = __shfl(sf, sbase + r);
                #pragma unroll
                for (int dt = 0; dt < 8; ++dt) {
                    Ov[qg][dt][0] *= sfr[0]; Ov[qg][dt][1] *= sfr[1];
                    Ov[qg][dt][2] *= sfr[2]; Ov[qg][dt][3] *= sfr[3];
                }
            }
            float p[4][4], s16 = 0.f;
            #pragma unroll
            for (int ct = 0; ct < 4; ++ct)
                #pragma unroll
                for (int r = 0; r < 4; ++r) { p[ct][r] = __expf(sc[qg][ct][r] - mrow[qg]); s16 += p[ct][r]; }
            s16 += __shfl_xor(s16, 16);
            s16 += __shfl_xor(s16, 32);
            lrow[qg] += s16;

            uint32 q0[4], q1[4];
            #pragma unroll
            for (int ct = 0; ct < 4; ++ct) {
                asm("v_cvt_pk_bf16_f32 %0, %1, %2" : "=v"(q0[ct]) : "v"(p[ct][0]), "v"(p[ct][1]));
                asm("v_cvt_pk_bf16_f32 %0, %1, %2" : "=v"(q1[ct]) : "v"(p[ct][2]), "v"(p[ct][3]));
            }
            #pragma unroll
            for (int ksl = 0; ksl < 2; ++ksl) {
                uint32 a0 = q0[2 * ksl], b0 = q0[2 * ksl + 1];
                uint32 a1 = q1[2 * ksl], b1 = q1[2 * ksl + 1];
                asm("v_permlane32_swap_b32 %0, %1" : "+v"(a0), "+v"(b0));
                asm("v_permlane16_swap_b32 %0, %1" : "+v"(a0), "+v"(b0));
                asm("v_permlane32_swap_b32 %0, %1" : "+v"(a1), "+v"(b1));
                asm("v_permlane16_swap_b32 %0, %1" : "+v"(a1), "+v"(b1));
                union { uint32 w4[4]; short8 s8; } pk_;
                pk_.w4[0] = a0; pk_.w4[1] = a1; pk_.w4[2] = b0; pk_.w4[3] = b1;
                pfq[qg][ksl] = pk_.s8;
            }
        }

        // --- PV: V read once per fragment, used by both query groups ---
        #pragma unroll
        for (int ksl = 0; ksl < 2; ++ksl)
            #pragma unroll
            for (int dt = 0; dt < 8; ++dt) {
                int d = dt * 16 + c;
                short8 vf = *(const short8*)&V1[d * 64 + (((ksl * 4 + u) ^ (d & 7)) << 3)];
                Ov[0][dt] = __builtin_amdgcn_mfma_f32_16x16x32_bf16(pfq[0][ksl], vf, Ov[0][dt], 0, 0, 0);
                Ov[1][dt] = __builtin_amdgcn_mfma_f32_16x16x32_bf16(pfq[1][ksl], vf, Ov[1][dt], 0, 0, 0);
            }

        __syncthreads();            // all waves done reading V1
        if (pre) WRITE_V();         // overwrite single V buffer with next tile
        __syncthreads();            // V1 (and K2[cur^1]) ready
    }

    // --- bf16 O partials + fp32 m/l ---
    size_t rbase = (size_t)slot * T_Q + qrow0;
    #pragma unroll
    for (int qg = 0; qg < 2; ++qg)
        #pragma unroll
        for (int dt = 0; dt < 8; ++dt)
            #pragma unroll
            for (int r = 0; r < 4; ++r)
                Opart[(rbase + qg * 16 + u * 4 + r) * 128 + dt * 16 + c] = f2bf(Ov[qg][dt][r]);
    if (u == 0) {
        mpart[rbase + c] = mrow[0];      lpart[rbase + c] = lrow[0];
        mpart[rbase + 16 + c] = mrow[1]; lpart[rbase + 16 + c] = lrow[1];
    }
}

// ---------------- combine partials + output bias + lambda head ----------------
__global__ __launch_bounds__(256) void combine_kernel(
    const ush* __restrict__ Opart, const float* __restrict__ mpart, const float* __restrict__ lpart,
    const float* __restrict__ bo_s, const float* __restrict__ bo_n,
    const float* __restrict__ Wl, const float* __restrict__ bl,
    const float* __restrict__ phi, float* __restrict__ outp)
{
    int row = blockIdx.x, tid = threadIdx.x;
    float outv;
    if (tid < 128) {               // self head: single partial (slot NSEG)
        size_t rb = (size_t)NSEG * T_Q + row;
        outv = bf2f(Opart[rb * 128 + tid]) / lpart[rb] + bo_s[tid];
    } else {                       // neighbor head: merge NSEG partials
        int d = tid - 128;
        float M = NEG_BIG;
        #pragma unroll
        for (int z = 0; z < NSEG; ++z) M = fmaxf(M, mpart[(size_t)z * T_Q + row]);
        float L = 0.f, O = 0.f;
        #pragma unroll
        for (int z = 0; z < NSEG; ++z) {
            size_t rb = (size_t)z * T_Q + row;
            float wz = __expf(mpart[rb] - M);
            L += wz * lpart[rb];
            O += wz * bf2f(Opart[rb * 128 + d]);
        }
        outv = O / L + bo_n[d];
    }
    outp[T_Q + (size_t)row * 256 + tid] = outv;

    float dot = outv * Wl[tid];
    #pragma unroll
    for (int off = 1; off < 64; off <<= 1) dot += __shfl_xor(dot, off);
    __shared__ float wsum[4];
    if ((tid & 63) == 0) wsum[tid >> 6] = dot;
    __syncthreads();
    if (tid == 0) {
        float s = wsum[0] + wsum[1] + wsum[2] + wsum[3];
        float ph = phi[0];
        float x = (s + bl[0]) * ph;
        x = fminf(x, 20.0f);
        outp[row] = log1pf(__expf(x)) / ph;
    }
}

extern "C" void kernel_launch(void* const* d_in, const int* in_sizes, int n_in,
                              void* d_out, int out_size, void* d_ws, size_t ws_size,
                              hipStream_t stream) {
    (void)in_sizes; (void)n_in; (void)out_size; (void)ws_size;
    const float* t    = (const float*)d_in[0];
    const float* ets  = (const float*)d_in[1];
    const int*   exps = (const int*)d_in[2];
    const int*   tgt  = (const int*)d_in[3];
    const float* bfq  = (const float*)d_in[4];
    const float* phi  = (const float*)d_in[5];
    const float* Wlin = (const float*)d_in[6];
    const float* blin = (const float*)d_in[7];
    const float* Wq_s = (const float*)d_in[8];
    const float* Wk_s = (const float*)d_in[9];
    const float* Wv_s = (const float*)d_in[10];
    const float* Wo_s = (const float*)d_in[11];
    const float* bq_s = (const float*)d_in[12];
    const float* bk_s = (const float*)d_in[13];
    const float* bv_s = (const float*)d_in[14];
    const float* bo_s = (const float*)d_in[15];
    const float* Wq_n = (const float*)d_in[16];
    const float* Wk_n = (const float*)d_in[17];
    const float* Wv_n = (const float*)d_in[18];
    const float* Wo_n = (const float*)d_in[19];
    const float* bq_n = (const float*)d_in[20];
    const float* bk_n = (const float*)d_in[21];
    const float* bv_n = (const float*)d_in[22];
    const float* bo_n = (const float*)d_in[23];

    char* ws = (char*)d_ws;
    size_t off = 0;
    auto alloc = [&](size_t bytes) { void* p = ws + off; off += (bytes + 255) & ~(size_t)255; return p; };
    ush* phi_t  = (ush*)alloc((size_t)T_Q * 128 * 2);
    ush* phi_ts = (ush*)alloc((size_t)S_ALLOC * 128 * 2);
    ush* qpb    = (ush*)alloc((size_t)2 * T_Q * 128 * 2);
    ush* kpc    = (ush*)alloc((size_t)(SELF_CAP + S_ALLOC) * 128 * 2);
    ush* vpoT   = (ush*)alloc((size_t)128 * (SELF_CAP + S_ALLOC) * 2);
    int*    perm1 = (int*)   alloc((size_t)SELF_CAP * 4);
    float*  ts1   = (float*) alloc((size_t)SELF_CAP * 4);
    float*  ts_pad= (float*) alloc((size_t)S_ALLOC * 4);
    u64*    maskb = (u64*)   alloc((size_t)NCH64 * 8);
    float*  bvo   = (float*) alloc((size_t)2 * 128 * 4);
    ush*    Wb    = (ush*)   alloc((size_t)6 * 16384 * 2);
    ush*    Opart = (ush*)   alloc((size_t)NSLOT * T_Q * 128 * 2);
    float*  mpart = (float*) alloc((size_t)NSLOT * T_Q * 4);
    float*  lpart = (float*) alloc((size_t)NSLOT * T_Q * 4);

    float* outp = (float*)d_out;

    prep_kernel<<<dim3(3473), dim3(256), 0, stream>>>(
        t, ets, exps, tgt, bfq, Wo_s, Wv_s, bv_s, Wo_n, Wv_n, bv_n,
        Wq_s, Wq_n, Wk_s, Wk_n, phi_t, phi_ts, ts_pad, ts1, perm1, maskb, Wb, bvo);
    proj_kernel<<<dim3(129, 6), dim3(256), 0, stream>>>(
        phi_t, phi_ts, Wb, bq_s, bq_n, bk_s, bk_n, bvo, perm1, qpb, kpc, vpoT);
    attn_kernel<<<dim3(32 * NSEG + 32), dim3(256), 0, stream>>>(
        qpb, kpc, vpoT, ts_pad, ts1, maskb, t, Opart, mpart, lpart);
    combine_kernel<<<dim3(T_Q), dim3(256), 0, stream>>>(
        Opart, mpart, lpart, bo_s, bo_n, Wlin, blin, phi, outp);
}